// Round 1
// baseline (658.954 us; speedup 1.0000x reference)
//
#include <hip/hip_runtime.h>

#define C_CLS 50
#define B_TR 8
#define T_FULL 600
#define T_USE 500
#define N_NEU 30000
#define CAP 1024
#define NBINS 16
#define EPS 1e-7

__device__ __constant__ int d_bins[NBINS] = {1,1,2,3,4,6,9,13,18,26,38,55,78,113,162,234};

// ---------------------------------------------------------------------------
// Kernel 0: detect how the harness encoded the bool sel_mask buffer.
// modes: 0=int32, 1=uint8, 2=float32, 3=int64, 4=float64
// We scan the first C*N/4 32-bit words (valid under every encoding, since the
// smallest possible buffer is C*N bytes = that many words) and classify by the
// bit patterns that nonzero entries produce.
// ---------------------------------------------------------------------------
__global__ void detect_mode_kernel(const void* mask, int* mode_out) {
    __shared__ int flags[4]; // 0: f32(0x3F800000), 1: byte-multi, 2: odd-word nonzero, 3: f64 hi word
    int tid = threadIdx.x;
    if (tid < 4) flags[tid] = 0;
    __syncthreads();
    const unsigned int* w = (const unsigned int*)mask;
    const int nwords = C_CLS * N_NEU / 4; // 375000
    int fF = 0, fB = 0, fO = 0, fD = 0;
    for (int i = tid; i < nwords; i += blockDim.x) {
        unsigned int v = w[i];
        if (v == 0u) continue;
        if (v == 0x3F800000u) fF = 1;
        else if (v == 0x3FF00000u && (i & 1)) fD = 1;
        else {
            unsigned int b0 = v & 0xFFu, b1 = (v >> 8) & 0xFFu,
                         b2 = (v >> 16) & 0xFFu, b3 = (v >> 24) & 0xFFu;
            bool byteOK = (b0 <= 1u) && (b1 <= 1u) && (b2 <= 1u) && (b3 <= 1u);
            if (byteOK && v != 1u) fB = 1;
        }
        if (i & 1) fO = 1;
    }
    if (fF) atomicOr(&flags[0], 1);
    if (fB) atomicOr(&flags[1], 1);
    if (fO) atomicOr(&flags[2], 1);
    if (fD) atomicOr(&flags[3], 1);
    __syncthreads();
    if (tid == 0) {
        int mode;
        if (flags[0]) mode = 2;        // float32 pattern seen
        else if (flags[3]) mode = 4;   // float64 pattern seen
        else if (flags[1]) mode = 1;   // packed bytes
        else if (flags[2]) mode = 0;   // 0/1 words incl. odd positions -> int32
        else mode = 3;                 // 0/1 only at even words -> int64
        *mode_out = mode;
    }
}

// ---------------------------------------------------------------------------
// Kernel 1: per-class selected-neuron index lists (compaction).
// Order within a list is nondeterministic, but it only feeds an exact
// integer-valued f32 sum, so the output is deterministic.
// ---------------------------------------------------------------------------
__global__ void build_lists_kernel(const void* mask, const int* mode_p,
                                   int* cnt, int* idx) {
    int c = blockIdx.x;
    int mode = *mode_p;
    __shared__ int sc;
    if (threadIdx.x == 0) sc = 0;
    __syncthreads();
    for (int n = threadIdx.x; n < N_NEU; n += blockDim.x) {
        long long e = (long long)c * N_NEU + n;
        bool sel;
        switch (mode) {
            case 0:  sel = ((const int*)mask)[e] != 0; break;
            case 1:  sel = ((const unsigned char*)mask)[e] != 0; break;
            case 2:  sel = ((const float*)mask)[e] != 0.0f; break;
            case 3:  sel = ((const long long*)mask)[e] != 0LL; break;
            default: sel = ((const double*)mask)[e] != 0.0; break;
        }
        if (sel) {
            int p = atomicAdd(&sc, 1);
            if (p < CAP) idx[c * CAP + p] = n;
        }
    }
    __syncthreads();
    if (threadIdx.x == 0) cnt[c] = min(sc, CAP);
}

// ---------------------------------------------------------------------------
// Kernel 2: gather selected[c][t] = sum over the class's ~70 neurons of
// spikes[trial(c), t, n]. Grid (C, 8) x 64 threads: one thread per (c,t).
// 16-way unrolled independent loads to keep ~16 VMEM ops in flight (each is
// a scattered HBM line fetch, ~900 cy latency).
// ---------------------------------------------------------------------------
__global__ void gather_kernel(const float* __restrict__ spikes,
                              const int* __restrict__ trials,
                              const int* __restrict__ cnt,
                              const int* __restrict__ idx,
                              float* __restrict__ selected) {
    int c = blockIdx.x;
    __shared__ int sidx[CAP];
    int kn = cnt[c];
    for (int k = threadIdx.x; k < kn; k += blockDim.x) sidx[k] = idx[c * CAP + k];
    __syncthreads();
    int b = trials[c];
    int t = blockIdx.y * blockDim.x + threadIdx.x;
    if (t >= T_USE) return;
    const float* __restrict__ row =
        spikes + ((long long)b * T_FULL + t) * N_NEU;
    float s = 0.f;
    int k = 0;
    for (; k + 16 <= kn; k += 16) {
        float p = 0.f;
#pragma unroll
        for (int u = 0; u < 16; ++u) p += row[sidx[k + u]];
        s += p;
    }
    for (; k < kn; ++k) s += row[sidx[k]];
    selected[c * T_USE + t] = s;
}

// ---------------------------------------------------------------------------
// Kernel 3: per-bin Fano factor averaged over classes. One block (1 wave)
// per bin; one lane per class; double accumulators (exact: counts are small
// integers).
// ---------------------------------------------------------------------------
__global__ void fano_kernel(const float* __restrict__ selected,
                            float* __restrict__ fanos) {
    int bin = blockIdx.x;
    int b = d_bins[bin];
    int nb = T_USE / b;
    int c = threadIdx.x;
    float fano = 0.f;
    if (c < C_CLS) {
        const float* row = selected + c * T_USE;
        double s1 = 0.0, s2 = 0.0;
        for (int i = 0; i < nb; ++i) {
            float cs = 0.f;
            int base = i * b;
            for (int j = 0; j < b; ++j) cs += row[base + j];
            s1 += cs;
            s2 += (double)cs * (double)cs;
        }
        double mean = s1 / nb;
        double var = s2 / nb - mean * mean;
        if (var < 0.0) var = 0.0;
        double m = mean > EPS ? mean : EPS;
        fano = (float)(var / m);
    }
    for (int off = 32; off > 0; off >>= 1) fano += __shfl_down(fano, off);
    if (threadIdx.x == 0) fanos[bin] = fano / (float)C_CLS;
}

// ---------------------------------------------------------------------------
// Kernel 4: final scalar loss = SYNC_COST * mean((exp - fano)^2)
// ---------------------------------------------------------------------------
__global__ void loss_kernel(const float* __restrict__ fanos,
                            const float* __restrict__ exp_fanos,
                            float* __restrict__ out) {
    int t = threadIdx.x;
    float sq = 0.f;
    if (t < NBINS) {
        float d = exp_fanos[t] - fanos[t];
        sq = d * d;
    }
    for (int off = 32; off > 0; off >>= 1) sq += __shfl_down(sq, off);
    if (t == 0) out[0] = 10.0f * sq / (float)NBINS;
}

extern "C" void kernel_launch(void* const* d_in, const int* in_sizes, int n_in,
                              void* d_out, int out_size, void* d_ws, size_t ws_size,
                              hipStream_t stream) {
    const float* spikes    = (const float*)d_in[0];
    const float* exp_fanos = (const float*)d_in[1];
    const int*   trials    = (const int*)d_in[2];
    const void*  mask      = d_in[3];
    float* out = (float*)d_out;

    char* ws = (char*)d_ws;
    int*   mode_p   = (int*)(ws + 0);
    int*   cnt      = (int*)(ws + 256);
    float* fanos    = (float*)(ws + 512);
    int*   idx      = (int*)(ws + 1024);
    float* selected = (float*)(ws + 1024 + (size_t)C_CLS * CAP * 4);
    // total ws use: ~306 KB

    detect_mode_kernel<<<1, 256, 0, stream>>>(mask, mode_p);
    build_lists_kernel<<<C_CLS, 256, 0, stream>>>(mask, mode_p, cnt, idx);
    gather_kernel<<<dim3(C_CLS, 8), 64, 0, stream>>>(spikes, trials, cnt, idx, selected);
    fano_kernel<<<NBINS, 64, 0, stream>>>(selected, fanos);
    loss_kernel<<<1, 64, 0, stream>>>(fanos, exp_fanos, out);
}

// Round 2
// 169.904 us; speedup vs baseline: 3.8784x; 3.8784x over previous
//
#include <hip/hip_runtime.h>

#define C_CLS 50
#define B_TR 8
#define T_FULL 600
#define T_USE 500
#define N_NEU 30000
#define CAP 1024
#define NBINS 16
#define EPS 1e-7

__device__ __constant__ int d_bins[NBINS] = {1,1,2,3,4,6,9,13,18,26,38,55,78,113,162,234};

// ---------------------------------------------------------------------------
// Kernel A: zero the detection flags (ws is poisoned 0xAA and never re-poisoned;
// we must init every launch for determinism).
// flags[0]: f32 pattern seen, [1]: multi-byte packed, [2]: odd-word nonzero,
// [3]: f64 hi-word pattern
// ---------------------------------------------------------------------------
__global__ void init_flags_kernel(int* flags) {
    if (threadIdx.x < 8) flags[threadIdx.x] = 0;
}

// ---------------------------------------------------------------------------
// Kernel B: detect how the harness encoded the bool sel_mask buffer.
// Grid-wide scan (512 blocks x 256 thr), one atomicOr per thread max.
// modes (derived later): 0=int32, 1=uint8, 2=float32, 3=int64, 4=float64
// ---------------------------------------------------------------------------
__global__ void detect_mode_kernel(const unsigned int* __restrict__ w, int* flags) {
    const int nwords = C_CLS * N_NEU / 4; // 375000 (smallest possible buffer)
    int stride = gridDim.x * blockDim.x;
    int fF = 0, fB = 0, fO = 0, fD = 0;
    for (int i = blockIdx.x * blockDim.x + threadIdx.x; i < nwords; i += stride) {
        unsigned int v = w[i];
        if (v == 0u) continue;
        if (v == 0x3F800000u) fF = 1;
        else if (v == 0x3FF00000u && (i & 1)) fD = 1;
        else {
            unsigned int b0 = v & 0xFFu, b1 = (v >> 8) & 0xFFu,
                         b2 = (v >> 16) & 0xFFu, b3 = (v >> 24) & 0xFFu;
            bool byteOK = (b0 <= 1u) && (b1 <= 1u) && (b2 <= 1u) && (b3 <= 1u);
            if (byteOK && v != 1u) fB = 1;
        }
        if (i & 1) fO = 1;
    }
    if (fF) atomicOr(&flags[0], 1);
    if (fB) atomicOr(&flags[1], 1);
    if (fO) atomicOr(&flags[2], 1);
    if (fD) atomicOr(&flags[3], 1);
}

__device__ __forceinline__ int mode_from_flags(const int* flags) {
    if (flags[0]) return 2;        // float32 pattern seen
    if (flags[3]) return 4;        // float64 pattern seen
    if (flags[1]) return 1;        // packed bytes
    if (flags[2]) return 0;        // 0/1 words incl. odd positions -> int32
    return 3;                      // 0/1 only at even words -> int64
}

// ---------------------------------------------------------------------------
// Kernel 1: per-class selected-neuron index lists (compaction).
// Order within a list is nondeterministic, but it only feeds an exact
// integer-valued f32 sum, so the output is deterministic.
// ---------------------------------------------------------------------------
__global__ void build_lists_kernel(const void* mask, const int* flags,
                                   int* cnt, int* idx) {
    int c = blockIdx.x;
    __shared__ int sc;
    __shared__ int smode;
    if (threadIdx.x == 0) { sc = 0; smode = mode_from_flags(flags); }
    __syncthreads();
    int mode = smode;
    for (int n = threadIdx.x; n < N_NEU; n += blockDim.x) {
        long long e = (long long)c * N_NEU + n;
        bool sel;
        switch (mode) {
            case 0:  sel = ((const int*)mask)[e] != 0; break;
            case 1:  sel = ((const unsigned char*)mask)[e] != 0; break;
            case 2:  sel = ((const float*)mask)[e] != 0.0f; break;
            case 3:  sel = ((const long long*)mask)[e] != 0LL; break;
            default: sel = ((const double*)mask)[e] != 0.0; break;
        }
        if (sel) {
            int p = atomicAdd(&sc, 1);
            if (p < CAP) idx[c * CAP + p] = n;
        }
    }
    __syncthreads();
    if (threadIdx.x == 0) cnt[c] = min(sc, CAP);
}

// ---------------------------------------------------------------------------
// Kernel 2: gather selected[c][t] = sum over the class's ~70 neurons of
// spikes[trial(c), t, n]. Grid (C, 8) x 64 threads: one thread per (c,t).
// 16-way unrolled independent loads to keep ~16 VMEM ops in flight (each is
// a scattered HBM/L2 fetch).
// ---------------------------------------------------------------------------
__global__ void gather_kernel(const float* __restrict__ spikes,
                              const int* __restrict__ trials,
                              const int* __restrict__ cnt,
                              const int* __restrict__ idx,
                              float* __restrict__ selected) {
    int c = blockIdx.x;
    __shared__ int sidx[CAP];
    int kn = cnt[c];
    for (int k = threadIdx.x; k < kn; k += blockDim.x) sidx[k] = idx[c * CAP + k];
    __syncthreads();
    int b = trials[c];
    int t = blockIdx.y * blockDim.x + threadIdx.x;
    if (t >= T_USE) return;
    const float* __restrict__ row =
        spikes + ((long long)b * T_FULL + t) * N_NEU;
    float s = 0.f;
    int k = 0;
    for (; k + 16 <= kn; k += 16) {
        float p = 0.f;
#pragma unroll
        for (int u = 0; u < 16; ++u) p += row[sidx[k + u]];
        s += p;
    }
    for (; k < kn; ++k) s += row[sidx[k]];
    selected[c * T_USE + t] = s;
}

// ---------------------------------------------------------------------------
// Kernel 3: per-bin Fano factor averaged over classes. One block (1 wave)
// per bin; one lane per class; double accumulators (exact: counts are small
// integers).
// ---------------------------------------------------------------------------
__global__ void fano_kernel(const float* __restrict__ selected,
                            float* __restrict__ fanos) {
    int bin = blockIdx.x;
    int b = d_bins[bin];
    int nb = T_USE / b;
    int c = threadIdx.x;
    float fano = 0.f;
    if (c < C_CLS) {
        const float* row = selected + c * T_USE;
        double s1 = 0.0, s2 = 0.0;
        for (int i = 0; i < nb; ++i) {
            float cs = 0.f;
            int base = i * b;
            for (int j = 0; j < b; ++j) cs += row[base + j];
            s1 += cs;
            s2 += (double)cs * (double)cs;
        }
        double mean = s1 / nb;
        double var = s2 / nb - mean * mean;
        if (var < 0.0) var = 0.0;
        double m = mean > EPS ? mean : EPS;
        fano = (float)(var / m);
    }
    for (int off = 32; off > 0; off >>= 1) fano += __shfl_down(fano, off);
    if (threadIdx.x == 0) fanos[bin] = fano / (float)C_CLS;
}

// ---------------------------------------------------------------------------
// Kernel 4: final scalar loss = SYNC_COST * mean((exp - fano)^2)
// ---------------------------------------------------------------------------
__global__ void loss_kernel(const float* __restrict__ fanos,
                            const float* __restrict__ exp_fanos,
                            float* __restrict__ out) {
    int t = threadIdx.x;
    float sq = 0.f;
    if (t < NBINS) {
        float d = exp_fanos[t] - fanos[t];
        sq = d * d;
    }
    for (int off = 32; off > 0; off >>= 1) sq += __shfl_down(sq, off);
    if (t == 0) out[0] = 10.0f * sq / (float)NBINS;
}

extern "C" void kernel_launch(void* const* d_in, const int* in_sizes, int n_in,
                              void* d_out, int out_size, void* d_ws, size_t ws_size,
                              hipStream_t stream) {
    const float* spikes    = (const float*)d_in[0];
    const float* exp_fanos = (const float*)d_in[1];
    const int*   trials    = (const int*)d_in[2];
    const void*  mask      = d_in[3];
    float* out = (float*)d_out;

    char* ws = (char*)d_ws;
    int*   flags    = (int*)(ws + 0);
    int*   cnt      = (int*)(ws + 256);
    float* fanos    = (float*)(ws + 512);
    int*   idx      = (int*)(ws + 1024);
    float* selected = (float*)(ws + 1024 + (size_t)C_CLS * CAP * 4);
    // total ws use: ~306 KB

    init_flags_kernel<<<1, 64, 0, stream>>>(flags);
    detect_mode_kernel<<<512, 256, 0, stream>>>((const unsigned int*)mask, flags);
    build_lists_kernel<<<C_CLS, 256, 0, stream>>>(mask, flags, cnt, idx);
    gather_kernel<<<dim3(C_CLS, 8), 64, 0, stream>>>(spikes, trials, cnt, idx, selected);
    fano_kernel<<<NBINS, 64, 0, stream>>>(selected, fanos);
    loss_kernel<<<1, 64, 0, stream>>>(fanos, exp_fanos, out);
}

// Round 3
// 169.622 us; speedup vs baseline: 3.8848x; 1.0017x over previous
//
#include <hip/hip_runtime.h>

#define C_CLS 50
#define B_TR 8
#define T_FULL 600
#define T_USE 500
#define N_NEU 30000
#define CAP 1024
#define NBINS 16
#define NSLICE 8
#define EPS 1e-7

__device__ __constant__ int d_bins[NBINS] = {1,1,2,3,4,6,9,13,18,26,38,55,78,113,162,234};

// ---------------------------------------------------------------------------
// Kernel A: zero the detection flags and the `selected` accumulator
// (ws is poisoned 0xAA once and never re-poisoned; gather uses atomicAdd).
// ---------------------------------------------------------------------------
__global__ void init_kernel(int* flags, float* selected) {
    int i = blockIdx.x * blockDim.x + threadIdx.x;
    if (i < 8) flags[i] = 0;
    if (i < C_CLS * T_USE) selected[i] = 0.0f;
}

// ---------------------------------------------------------------------------
// Kernel B: detect how the harness encoded the bool sel_mask buffer.
// Grid-wide scan, one atomicOr per thread max.
// modes (derived later): 0=int32, 1=uint8, 2=float32, 3=int64, 4=float64
// ---------------------------------------------------------------------------
__global__ void detect_mode_kernel(const unsigned int* __restrict__ w, int* flags) {
    const int nwords = C_CLS * N_NEU / 4; // 375000 (smallest possible buffer)
    int stride = gridDim.x * blockDim.x;
    int fF = 0, fB = 0, fO = 0, fD = 0;
    for (int i = blockIdx.x * blockDim.x + threadIdx.x; i < nwords; i += stride) {
        unsigned int v = w[i];
        if (v == 0u) continue;
        if (v == 0x3F800000u) fF = 1;
        else if (v == 0x3FF00000u && (i & 1)) fD = 1;
        else {
            unsigned int b0 = v & 0xFFu, b1 = (v >> 8) & 0xFFu,
                         b2 = (v >> 16) & 0xFFu, b3 = (v >> 24) & 0xFFu;
            bool byteOK = (b0 <= 1u) && (b1 <= 1u) && (b2 <= 1u) && (b3 <= 1u);
            if (byteOK && v != 1u) fB = 1;
        }
        if (i & 1) fO = 1;
    }
    if (fF) atomicOr(&flags[0], 1);
    if (fB) atomicOr(&flags[1], 1);
    if (fO) atomicOr(&flags[2], 1);
    if (fD) atomicOr(&flags[3], 1);
}

__device__ __forceinline__ int mode_from_flags(const int* flags) {
    if (flags[0]) return 2;        // float32 pattern seen
    if (flags[3]) return 4;        // float64 pattern seen
    if (flags[1]) return 1;        // packed bytes
    if (flags[2]) return 0;        // 0/1 words incl. odd positions -> int32
    return 3;                      // 0/1 only at even words -> int64
}

// ---------------------------------------------------------------------------
// Kernel 1: per-class selected-neuron index lists (compaction).
// Order within a list is nondeterministic, but it only feeds an exact
// integer-valued f32 sum, so the output is deterministic.
// ---------------------------------------------------------------------------
__global__ void build_lists_kernel(const void* mask, const int* flags,
                                   int* cnt, int* idx) {
    int c = blockIdx.x;
    __shared__ int sc;
    __shared__ int smode;
    if (threadIdx.x == 0) { sc = 0; smode = mode_from_flags(flags); }
    __syncthreads();
    int mode = smode;
    for (int n = threadIdx.x; n < N_NEU; n += blockDim.x) {
        long long e = (long long)c * N_NEU + n;
        bool sel;
        switch (mode) {
            case 0:  sel = ((const int*)mask)[e] != 0; break;
            case 1:  sel = ((const unsigned char*)mask)[e] != 0; break;
            case 2:  sel = ((const float*)mask)[e] != 0.0f; break;
            case 3:  sel = ((const long long*)mask)[e] != 0LL; break;
            default: sel = ((const double*)mask)[e] != 0.0; break;
        }
        if (sel) {
            int p = atomicAdd(&sc, 1);
            if (p < CAP) idx[c * CAP + p] = n;
        }
    }
    __syncthreads();
    if (threadIdx.x == 0) cnt[c] = min(sc, CAP);
}

// ---------------------------------------------------------------------------
// Kernel 2: gather. selected[c][t] += partial sums over a slice of the
// class's ~70 neurons. Grid (C, 8 t-blocks, NSLICE k-slices) x 64 threads.
// Slice s owns neuron-list entries k = s, s+NSLICE, ... Each thread issues
// its ~kn/NSLICE loads as one unconditional 16-deep burst (list padded in
// LDS; out-of-range entries multiplied by 0 via cndmask, no branch).
// 3200 waves (~12/CU) to saturate random-64B-line HBM bandwidth.
// Partial sums are exact small integers in f32 -> atomicAdd is
// order-independent and deterministic.
// ---------------------------------------------------------------------------
__global__ void gather_kernel(const float* __restrict__ spikes,
                              const int* __restrict__ trials,
                              const int* __restrict__ cnt,
                              const int* __restrict__ idx,
                              float* __restrict__ selected) {
    int c = blockIdx.x;
    __shared__ int sidx[CAP + 16 * NSLICE];
    int kn = cnt[c];
    int pad = idx[c * CAP];  // valid index to use for padded entries
    for (int k = threadIdx.x; k < kn; k += blockDim.x) sidx[k] = idx[c * CAP + k];
    for (int k = kn + threadIdx.x; k < kn + 16 * NSLICE; k += blockDim.x) sidx[k] = pad;
    __syncthreads();
    int b = trials[c];
    int t = blockIdx.y * blockDim.x + threadIdx.x;
    if (t >= T_USE) return;
    int s = blockIdx.z;
    const float* __restrict__ row =
        spikes + ((long long)b * T_FULL + t) * N_NEU;
    float acc = 0.f;
    for (int kk = s; kk < kn; kk += 16 * NSLICE) {
        float v[16];
#pragma unroll
        for (int u = 0; u < 16; ++u) {
            int k2 = kk + u * NSLICE;
            v[u] = row[sidx[k2]] * ((k2 < kn) ? 1.0f : 0.0f);
        }
#pragma unroll
        for (int u = 0; u < 16; ++u) acc += v[u];
    }
    atomicAdd(&selected[c * T_USE + t], acc);
}

// ---------------------------------------------------------------------------
// Kernel 3: per-bin Fano factor averaged over classes. One block (1 wave)
// per bin; one lane per class; double accumulators (exact: counts are small
// integers).
// ---------------------------------------------------------------------------
__global__ void fano_kernel(const float* __restrict__ selected,
                            float* __restrict__ fanos) {
    int bin = blockIdx.x;
    int b = d_bins[bin];
    int nb = T_USE / b;
    int c = threadIdx.x;
    float fano = 0.f;
    if (c < C_CLS) {
        const float* row = selected + c * T_USE;
        double s1 = 0.0, s2 = 0.0;
        for (int i = 0; i < nb; ++i) {
            float cs = 0.f;
            int base = i * b;
            for (int j = 0; j < b; ++j) cs += row[base + j];
            s1 += cs;
            s2 += (double)cs * (double)cs;
        }
        double mean = s1 / nb;
        double var = s2 / nb - mean * mean;
        if (var < 0.0) var = 0.0;
        double m = mean > EPS ? mean : EPS;
        fano = (float)(var / m);
    }
    for (int off = 32; off > 0; off >>= 1) fano += __shfl_down(fano, off);
    if (threadIdx.x == 0) fanos[bin] = fano / (float)C_CLS;
}

// ---------------------------------------------------------------------------
// Kernel 4: final scalar loss = SYNC_COST * mean((exp - fano)^2)
// ---------------------------------------------------------------------------
__global__ void loss_kernel(const float* __restrict__ fanos,
                            const float* __restrict__ exp_fanos,
                            float* __restrict__ out) {
    int t = threadIdx.x;
    float sq = 0.f;
    if (t < NBINS) {
        float d = exp_fanos[t] - fanos[t];
        sq = d * d;
    }
    for (int off = 32; off > 0; off >>= 1) sq += __shfl_down(sq, off);
    if (t == 0) out[0] = 10.0f * sq / (float)NBINS;
}

extern "C" void kernel_launch(void* const* d_in, const int* in_sizes, int n_in,
                              void* d_out, int out_size, void* d_ws, size_t ws_size,
                              hipStream_t stream) {
    const float* spikes    = (const float*)d_in[0];
    const float* exp_fanos = (const float*)d_in[1];
    const int*   trials    = (const int*)d_in[2];
    const void*  mask      = d_in[3];
    float* out = (float*)d_out;

    char* ws = (char*)d_ws;
    int*   flags    = (int*)(ws + 0);
    int*   cnt      = (int*)(ws + 256);
    float* fanos    = (float*)(ws + 512);
    int*   idx      = (int*)(ws + 1024);
    float* selected = (float*)(ws + 1024 + (size_t)C_CLS * CAP * 4);
    // total ws use: ~306 KB

    init_kernel<<<(C_CLS * T_USE + 255) / 256, 256, 0, stream>>>(flags, selected);
    detect_mode_kernel<<<512, 256, 0, stream>>>((const unsigned int*)mask, flags);
    build_lists_kernel<<<C_CLS, 256, 0, stream>>>(mask, flags, cnt, idx);
    gather_kernel<<<dim3(C_CLS, 8, NSLICE), 64, 0, stream>>>(spikes, trials, cnt, idx, selected);
    fano_kernel<<<NBINS, 64, 0, stream>>>(selected, fanos);
    loss_kernel<<<1, 64, 0, stream>>>(fanos, exp_fanos, out);
}